// Round 7
// baseline (226.291 us; speedup 1.0000x reference)
//
#include <hip/hip_runtime.h>

#define S_LEN  4096
#define DMODEL 512
#define NH     8
#define HD     64

typedef _Float16 f16x8 __attribute__((ext_vector_type(8)));
typedef _Float16 f16x4 __attribute__((ext_vector_type(4)));
typedef float    f32x4 __attribute__((ext_vector_type(4)));

static __device__ __forceinline__ unsigned short f2h(float x) {
  return __builtin_bit_cast(unsigned short, (_Float16)x);
}

// ---------------------------------------------------------------------------
// Weight transpose + fp32->fp16: Wt[n][k] = (fp16) W[k][n].  For z==3 (Wo)
// also emits the straight fp16 copy Wof[k][n].  grid (8,8,4) block 256
// ---------------------------------------------------------------------------
__global__ __launch_bounds__(256) void wtrans_kernel(
    const float* __restrict__ w0, const float* __restrict__ w1,
    const float* __restrict__ w2, const float* __restrict__ w3,
    unsigned short* __restrict__ o0, unsigned short* __restrict__ o1,
    unsigned short* __restrict__ o2, unsigned short* __restrict__ o3,
    unsigned short* __restrict__ o3s)
{
  __shared__ unsigned short T[64 * 72];   // T[n_local][k_local], pad 72
  const float* W; unsigned short* O;
  switch (blockIdx.z) {
    case 0:  W = w0; O = o0; break;
    case 1:  W = w1; O = o1; break;
    case 2:  W = w2; O = o2; break;
    default: W = w3; O = o3; break;
  }
  const int tid = threadIdx.x;
  const int k0 = blockIdx.x * 64, n0 = blockIdx.y * 64;
  const int c4 = (tid & 15) * 4;
#pragma unroll
  for (int rp = 0; rp < 4; ++rp) {
    int r = rp * 16 + (tid >> 4);
    float4 x = *(const float4*)(W + (k0 + r) * DMODEL + n0 + c4);
    T[(c4 + 0) * 72 + r] = f2h(x.x);
    T[(c4 + 1) * 72 + r] = f2h(x.y);
    T[(c4 + 2) * 72 + r] = f2h(x.z);
    T[(c4 + 3) * 72 + r] = f2h(x.w);
    if (blockIdx.z == 3) {
      f16x4 st;
      st[0] = (_Float16)x.x; st[1] = (_Float16)x.y;
      st[2] = (_Float16)x.z; st[3] = (_Float16)x.w;
      *(f16x4*)&o3s[(k0 + r) * DMODEL + n0 + c4] = st;
    }
  }
  __syncthreads();
#pragma unroll
  for (int it = 0; it < 2; ++it) {
    int i = tid + it * 256;
    int nl = i >> 3, c = i & 7;
    *(f16x8*)&O[(n0 + nl) * DMODEL + k0 + c * 8] = *(const f16x8*)&T[nl * 72 + c * 8];
  }
}

// ---------------------------------------------------------------------------
// 128x128-tile GEMM (multi-op), BK=32, 4 waves x (4x4 16x16x32 frags),
// register-prefetch staging (round-4 proven config).
// blockIdx.z selects op; z==3: x<4 -> Wo2t 128-tiles (M=512), x in 4..11 &
// y==0 -> bo2 side-job. vtg!=null && z==2: C stored transposed (V^T).
// grid (32,4,nz) block 256.
// ---------------------------------------------------------------------------
__global__ __launch_bounds__(256) void gemm128_kernel(
    const void* __restrict__ A0, const void* __restrict__ A1,
    const void* __restrict__ A2, const void* __restrict__ A3,
    const unsigned short* __restrict__ B0, const unsigned short* __restrict__ B1,
    const unsigned short* __restrict__ B2, const unsigned short* __restrict__ B3,
    void* __restrict__ C0, void* __restrict__ C1,
    void* __restrict__ C2, void* __restrict__ C3,
    const float* __restrict__ bias, unsigned short* __restrict__ vtg,
    const float* __restrict__ wo_f32, const float* __restrict__ bo_in,
    float* __restrict__ bo2_out,
    int a_fp32_mask, int c_fp32_mask)
{
  constexpr int K = DMODEL, N = DMODEL;
  __shared__ unsigned short As[128 * 32];
  __shared__ unsigned short Bs[128 * 32];
  const int z = blockIdx.z;
  if (z == 3 && blockIdx.x >= 4) {          // idle tiles: bo2 side-job
    if (blockIdx.x < 12 && blockIdx.y == 0 && wo_f32) {
      int col = (blockIdx.x - 4) * 64 + (threadIdx.x & 63);
      float s = bo_in[col];
#pragma unroll 8
      for (int j = 0; j < DMODEL; ++j) s = fmaf(bo_in[j], wo_f32[j * DMODEL + col], s);
      bo2_out[col] = s;
    }
    return;
  }
  const void* Av; const unsigned short* Bt; void* Cv;
  switch (z) {
    case 0:  Av = A0; Bt = B0; Cv = C0; break;
    case 1:  Av = A1; Bt = B1; Cv = C1; break;
    case 2:  Av = A2; Bt = B2; Cv = C2; break;
    default: Av = A3; Bt = B3; Cv = C3; break;
  }
  const int a_fp32 = (a_fp32_mask >> z) & 1;
  const int c_fp32 = (c_fp32_mask >> z) & 1;
  const int tid  = threadIdx.x;
  const int lane = tid & 63;
  const int wid  = tid >> 6;
  const int quad = lane >> 4, l16 = lane & 15;
  const int m0 = blockIdx.x * 128, n0 = blockIdx.y * 128;
  const int wm = (wid >> 1) * 64, wn = (wid & 1) * 64;
  f32x4 acc[4][4] = {};

  // staging decomposition: it in 0..1: s = it*256+tid; r = s>>2; ck = (s&3)*8
  f16x8 areg[2], breg[2];
#pragma unroll
  for (int it = 0; it < 2; ++it) {      // prefetch k0 = 0
    int s = it * 256 + tid;
    int r = s >> 2, ck = (s & 3) * 8;
    if (a_fp32) {
      const float* p = (const float*)Av + (m0 + r) * K + ck;
      float4 x = *(const float4*)p;
      float4 y = *(const float4*)(p + 4);
      f16x8 av;
      av[0] = (_Float16)x.x; av[1] = (_Float16)x.y;
      av[2] = (_Float16)x.z; av[3] = (_Float16)x.w;
      av[4] = (_Float16)y.x; av[5] = (_Float16)y.y;
      av[6] = (_Float16)y.z; av[7] = (_Float16)y.w;
      areg[it] = av;
    } else {
      areg[it] = *(const f16x8*)((const unsigned short*)Av + (m0 + r) * K + ck);
    }
    breg[it] = *(const f16x8*)(Bt + (n0 + r) * K + ck);
  }

  for (int k0 = 0; k0 < K; k0 += 32) {
    __syncthreads();
#pragma unroll
    for (int it = 0; it < 2; ++it) {
      int s = it * 256 + tid;
      int r = s >> 2, ck = (s & 3) * 8;
      *(f16x8*)&As[r * 32 + ck] = areg[it];
      *(f16x8*)&Bs[r * 32 + ck] = breg[it];
    }
    __syncthreads();

    if (k0 + 32 < K) {                  // prefetch next k-step into registers
      int kk = k0 + 32;
#pragma unroll
      for (int it = 0; it < 2; ++it) {
        int s = it * 256 + tid;
        int r = s >> 2, ck = (s & 3) * 8;
        if (a_fp32) {
          const float* p = (const float*)Av + (m0 + r) * K + kk + ck;
          float4 x = *(const float4*)p;
          float4 y = *(const float4*)(p + 4);
          f16x8 av;
          av[0] = (_Float16)x.x; av[1] = (_Float16)x.y;
          av[2] = (_Float16)x.z; av[3] = (_Float16)x.w;
          av[4] = (_Float16)y.x; av[5] = (_Float16)y.y;
          av[6] = (_Float16)y.z; av[7] = (_Float16)y.w;
          areg[it] = av;
        } else {
          areg[it] = *(const f16x8*)((const unsigned short*)Av + (m0 + r) * K + kk + ck);
        }
        breg[it] = *(const f16x8*)(Bt + (n0 + r) * K + kk + ck);
      }
    }

    f16x8 af[4], bf[4];
#pragma unroll
    for (int mt = 0; mt < 4; ++mt)
      af[mt] = *(const f16x8*)&As[(wm + mt * 16 + l16) * 32 + quad * 8];
#pragma unroll
    for (int nt = 0; nt < 4; ++nt)
      bf[nt] = *(const f16x8*)&Bs[(wn + nt * 16 + l16) * 32 + quad * 8];
#pragma unroll
    for (int mt = 0; mt < 4; ++mt)
#pragma unroll
      for (int nt = 0; nt < 4; ++nt)
        acc[mt][nt] = __builtin_amdgcn_mfma_f32_16x16x32_f16(af[mt], bf[nt], acc[mt][nt], 0, 0, 0);
  }

  const int do_vt = (vtg != nullptr) && (z == 2);
#pragma unroll
  for (int mt = 0; mt < 4; ++mt)
#pragma unroll
    for (int nt = 0; nt < 4; ++nt) {
      int col = n0 + wn + nt * 16 + l16;
      float bv = bias ? bias[col] : 0.f;
#pragma unroll
      for (int g = 0; g < 4; ++g) {
        int row = m0 + wm + mt * 16 + quad * 4 + g;   // C/D: row = quad*4+reg
        float val = acc[mt][nt][g] + bv;
        if (do_vt)        vtg[col * S_LEN + row] = f2h(val);      // V^T[d][key]
        else if (c_fp32)  ((float*)Cv)[row * N + col] = val;
        else              ((unsigned short*)Cv)[row * N + col] = f2h(val);
      }
    }
}

// ---------------------------------------------------------------------------
// Split-K MFMA flash attention, S^T formulation, 2 q-sets per wave.
// 128 q-rows per block (4 waves = 4 q-pairs; K/V traffic-optimal, round 6:
// -12%). ROUND CHANGE: KVBLK 64 -> 128 (iters 32 -> 16 per z-chunk).
// Rationale: at ~2 resident waves/SIMD (occupancy invariant across all
// grid shapes, rounds 0-6), per-iteration FIXED costs are exposed serial
// time: 2 barriers, shuffle-reduce trees, o-rescale, defer branch, staging
// address math. Halving iteration count halves them; per-key exp/MFMA
// unchanged. PV restructured to batch the 4 Vt reads per kt before the
// 8 MFMAs. LDS 27.6 KB: Ks[128][72] + Vt[64 d][128 k] XOR-swizzled
// (granule (2c+j)^(d&15); reads conflict-free, writes at 4-phase minimum).
// grid (32, 8, 2); z handles keys [z*2048, z*2048+2048).
// Partials: z=0 -> f32 in d_out, z=1 -> fp16 in Ab; (m,l) to ws;
// merge_kernel combines.
// ---------------------------------------------------------------------------
__global__ __launch_bounds__(256) void attn_kernel(
    const unsigned short* __restrict__ Qb, const unsigned short* __restrict__ Kb,
    const unsigned short* __restrict__ VtG,
    float* __restrict__ P0, unsigned short* __restrict__ P1,
    float* __restrict__ mp, float* __restrict__ lp)
{
  __shared__ unsigned short Ks[128 * 72];   // K[key][d], pad 72
  __shared__ unsigned short Vt[64 * 128];   // V^T[d][key] swizzled, no pad

  const int tid  = threadIdx.x;
  const int lane = tid & 63;
  const int wid  = tid >> 6;        // 0..3 = q-pair
  const int quad = lane >> 4, l16 = lane & 15;
  const int qb = blockIdx.x, h = blockIdx.y, z = blockIdx.z;
  const int hc = h * HD;
  const int qbase = qb * 128 + wid * 32;
  const int kz = z * 2048;

  // Persistent Q fragments (B operand), 2 sets: Q[q=l16][d=quad*8+j (+32)]
  f16x8 bq[2][2];
#pragma unroll
  for (int s = 0; s < 2; ++s) {
    int qrow = qbase + s * 16 + l16;
    bq[s][0] = *(const f16x8*)(Qb + qrow * DMODEL + hc + quad * 8);
    bq[s][1] = *(const f16x8*)(Qb + qrow * DMODEL + hc + 32 + quad * 8);
  }

  // o[s][nt] holds O[q = quad*4+g][d = nt*16 + l16] for set s
  f32x4 o[2][4] = {};
  float m_run[2] = {-1e30f, -1e30f}, l_run[2] = {0.f, 0.f};

  // staging decomposition (256 threads, 1024 16B-chunks per array):
  // K: s = it*256+tid; n = s>>3 (key row 0..127); c = s&7
  // V: s = it*256+tid; d = s>>4 (d row 0..63);   c = s&15
  f16x8 kreg[4], vreg[4];
#pragma unroll
  for (int it = 0; it < 4; ++it) {     // prefetch kbi = 0
    int s = it * 256 + tid;
    int kn = s >> 3, kc = s & 7;
    int vd = s >> 4, vc = s & 15;
    kreg[it] = *(const f16x8*)(Kb + (kz + kn) * DMODEL + hc + kc * 8);
    vreg[it] = *(const f16x8*)(VtG + (hc + vd) * S_LEN + kz + vc * 8);
  }

  for (int kbi = 0; kbi < 16; ++kbi) {
    __syncthreads();                   // all waves done reading previous tile
#pragma unroll
    for (int it = 0; it < 4; ++it) {
      int s = it * 256 + tid;
      int kn = s >> 3, kc = s & 7;
      *(f16x8*)&Ks[kn * 72 + kc * 8] = kreg[it];
      // swizzled Vt: granule (2c+j) of row d at slot ((2c+j)^(d&15)), 32/row
      int vd = s >> 4, vc = s & 15;
      int vbase = vd * 32;
      int d15 = vd & 15;
      f16x4 lo = __builtin_shufflevector(vreg[it], vreg[it], 0, 1, 2, 3);
      f16x4 hi = __builtin_shufflevector(vreg[it], vreg[it], 4, 5, 6, 7);
      *(f16x4*)&Vt[(vbase + ((2 * vc) ^ d15)) * 4]     = lo;
      *(f16x4*)&Vt[(vbase + ((2 * vc + 1) ^ d15)) * 4] = hi;
    }
    __syncthreads();                   // staging visible

    if (kbi + 1 < 16) {                // prefetch next 128-key tile into regs
      int kb1 = kz + (kbi + 1) * 128;
#pragma unroll
      for (int it = 0; it < 4; ++it) {
        int s = it * 256 + tid;
        int kn = s >> 3, kc = s & 7;
        int vd = s >> 4, vc = s & 15;
        kreg[it] = *(const f16x8*)(Kb + (kb1 + kn) * DMODEL + hc + kc * 8);
        vreg[it] = *(const f16x8*)(VtG + (hc + vd) * S_LEN + kb1 + vc * 8);
      }
    }

    // ---- S^T = K Q^T : one Ks read feeds both q-sets (kt = 16-key group)
    f32x4 sT[2][8];
#pragma unroll
    for (int kt = 0; kt < 8; ++kt) {
      f16x8 ak0 = *(const f16x8*)&Ks[(kt * 16 + l16) * 72 + quad * 8];
      f16x8 ak1 = *(const f16x8*)&Ks[(kt * 16 + l16) * 72 + 32 + quad * 8];
#pragma unroll
      for (int s = 0; s < 2; ++s) {
        f32x4 a = {};
        a = __builtin_amdgcn_mfma_f32_16x16x32_f16(ak0, bq[s][0], a, 0, 0, 0);
        a = __builtin_amdgcn_mfma_f32_16x16x32_f16(ak1, bq[s][1], a, 0, 0, 0);
        sT[s][kt] = a;
      }
    }

    // ---- online softmax per set (scale 1/8 folded into exp), defer-max
    f16x4 pa[2][8];
#pragma unroll
    for (int s = 0; s < 2; ++s) {
      float vmax = -1e30f;
#pragma unroll
      for (int kt = 0; kt < 8; ++kt)
#pragma unroll
        for (int g = 0; g < 4; ++g) vmax = fmaxf(vmax, sT[s][kt][g]);
      vmax = fmaxf(vmax, __shfl_xor(vmax, 16));
      vmax = fmaxf(vmax, __shfl_xor(vmax, 32));

      if (__all(vmax <= m_run[s] + 8.0f)) {
        // deferred: keep old max, no rescale; p bounded by e^1
        const float mn = m_run[s];
        float rs = 0.f;
#pragma unroll
        for (int kt = 0; kt < 8; ++kt)
#pragma unroll
          for (int g = 0; g < 4; ++g) {
            float p = __expf((sT[s][kt][g] - mn) * 0.125f);
            rs += p;
            pa[s][kt][g] = (_Float16)p;
          }
        rs += __shfl_xor(rs, 16);
        rs += __shfl_xor(rs, 32);
        l_run[s] += rs;
      } else {
        const float mn = fmaxf(m_run[s], vmax);
        const float alpha = __expf((m_run[s] - mn) * 0.125f);
        m_run[s] = mn;

        float rs = 0.f;
#pragma unroll
        for (int kt = 0; kt < 8; ++kt)
#pragma unroll
          for (int g = 0; g < 4; ++g) {
            float p = __expf((sT[s][kt][g] - mn) * 0.125f);
            rs += p;
            pa[s][kt][g] = (_Float16)p;
          }
        rs += __shfl_xor(rs, 16);
        rs += __shfl_xor(rs, 32);
        l_run[s] = l_run[s] * alpha + rs;

        float ag[4];
#pragma unroll
        for (int g = 0; g < 4; ++g) ag[g] = __shfl(alpha, quad * 4 + g);
#pragma unroll
        for (int nt = 0; nt < 4; ++nt)
#pragma unroll
          for (int g = 0; g < 4; ++g) o[s][nt][g] *= ag[g];
      }
    }

    // ---- O += P @ V : per kt, batch 4 swizzled Vt b64 reads, then 8 MFMAs
#pragma unroll
    for (int kt = 0; kt < 8; ++kt) {
      f16x4 bv[4];
#pragma unroll
      for (int nt = 0; nt < 4; ++nt) {
        int d = nt * 16 + l16;
        bv[nt] = *(const f16x4*)&Vt[(d * 32 + ((kt * 4 + quad) ^ l16)) * 4];
      }
#pragma unroll
      for (int nt = 0; nt < 4; ++nt)
#pragma unroll
        for (int s = 0; s < 2; ++s)
          o[s][nt] = __builtin_amdgcn_mfma_f32_16x16x16f16(pa[s][kt], bv[nt], o[s][nt], 0, 0, 0);
    }
  }

  // ---- no intra-block merge: each wave owns its 32 q-rows. Store partial.
#pragma unroll
  for (int s = 0; s < 2; ++s) {
    const float lt = l_run[s];
    const float rl = 1.f / lt;
    if (quad == 0) {                   // per-row (m,l) for cross-block merge
      int q = qbase + s * 16 + l16;
      mp[(z * NH + h) * S_LEN + q] = m_run[s];
      lp[(z * NH + h) * S_LEN + q] = lt;
    }
    float rlg[4];
#pragma unroll
    for (int g = 0; g < 4; ++g) rlg[g] = __shfl(rl, quad * 4 + g);
#pragma unroll
    for (int g = 0; g < 4; ++g) {
      int row = qbase + s * 16 + quad * 4 + g;
#pragma unroll
      for (int nt = 0; nt < 4; ++nt) {
        float val = o[s][nt][g] * rlg[g];   // normalized partial
        if (z == 0) P0[row * DMODEL + hc + nt * 16 + l16] = val;
        else        P1[row * DMODEL + hc + nt * 16 + l16] = f2h(val);
      }
    }
  }
}

// ---------------------------------------------------------------------------
// Cross-block merge of the two key-split partials: Ab = w0*P0 + w1*P1.
// grid (64, 8) block 256: thread = (row r = tid>>2, 16 d at (tid&3)*16).
// ---------------------------------------------------------------------------
__global__ __launch_bounds__(256) void merge_kernel(
    const float* __restrict__ P0, const unsigned short* __restrict__ P1,
    const float* __restrict__ mp, const float* __restrict__ lp,
    unsigned short* __restrict__ Ob)
{
  const int tid = threadIdx.x;
  const int qb = blockIdx.x, h = blockIdx.y;
  const int q = qb * 64 + (tid >> 2), hc = h * HD;
  const int dq = (tid & 3) * 16;
  const float m0 = mp[h * S_LEN + q],        l0 = lp[h * S_LEN + q];
  const float m1 = mp[(NH + h) * S_LEN + q], l1 = lp[(NH + h) * S_LEN + q];
  const float M  = fmaxf(m0, m1);
  float w0 = l0 * __expf((m0 - M) * 0.125f);
  float w1 = l1 * __expf((m1 - M) * 0.125f);
  const float rw = 1.f / (w0 + w1);
  w0 *= rw; w1 *= rw;
  const int base = q * DMODEL + hc + dq;
  f16x8 p1a = *(const f16x8*)&P1[base];
  f16x8 p1b = *(const f16x8*)&P1[base + 8];
  float4 x0 = *(const float4*)&P0[base];
  float4 x1 = *(const float4*)&P0[base + 4];
  float4 x2 = *(const float4*)&P0[base + 8];
  float4 x3 = *(const float4*)&P0[base + 12];
  f16x8 oa, ob;
  oa[0] = (_Float16)(w0 * x0.x + w1 * (float)p1a[0]);
  oa[1] = (_Float16)(w0 * x0.y + w1 * (float)p1a[1]);
  oa[2] = (_Float16)(w0 * x0.z + w1 * (float)p1a[2]);
  oa[3] = (_Float16)(w0 * x0.w + w1 * (float)p1a[3]);
  oa[4] = (_Float16)(w0 * x1.x + w1 * (float)p1a[4]);
  oa[5] = (_Float16)(w0 * x1.y + w1 * (float)p1a[5]);
  oa[6] = (_Float16)(w0 * x1.z + w1 * (float)p1a[6]);
  oa[7] = (_Float16)(w0 * x1.w + w1 * (float)p1a[7]);
  ob[0] = (_Float16)(w0 * x2.x + w1 * (float)p1b[0]);
  ob[1] = (_Float16)(w0 * x2.y + w1 * (float)p1b[1]);
  ob[2] = (_Float16)(w0 * x2.z + w1 * (float)p1b[2]);
  ob[3] = (_Float16)(w0 * x2.w + w1 * (float)p1b[3]);
  ob[4] = (_Float16)(w0 * x3.x + w1 * (float)p1b[4]);
  ob[5] = (_Float16)(w0 * x3.y + w1 * (float)p1b[5]);
  ob[6] = (_Float16)(w0 * x3.z + w1 * (float)p1b[6]);
  ob[7] = (_Float16)(w0 * x3.w + w1 * (float)p1b[7]);
  *(f16x8*)&Ob[base]     = oa;
  *(f16x8*)&Ob[base + 8] = ob;
}

// ---------------------------------------------------------------------------
extern "C" void kernel_launch(void* const* d_in, const int* in_sizes, int n_in,
                              void* d_out, int out_size, void* d_ws, size_t ws_size,
                              hipStream_t stream) {
  const float* q  = (const float*)d_in[0];
  const float* k  = (const float*)d_in[1];
  const float* v  = (const float*)d_in[2];
  const float* Wq = (const float*)d_in[3];
  const float* Wk = (const float*)d_in[4];
  const float* Wv = (const float*)d_in[5];
  const float* Wo = (const float*)d_in[6];
  const float* bo = (const float*)d_in[7];

  unsigned short* ws   = (unsigned short*)d_ws;
  unsigned short* Wqt  = ws;                  // 512*512 fp16 each
  unsigned short* Wkt  = Wqt  + 262144;
  unsigned short* Wvt  = Wkt  + 262144;
  unsigned short* Wot  = Wvt  + 262144;
  unsigned short* Wof  = Wot  + 262144;       // straight fp16 Wo
  unsigned short* Wo2t = Wof  + 262144;       // (Wo^2)^T fp16
  unsigned short* Qb   = Wo2t + 262144;       // 4096*512 fp16 each
  unsigned short* Kb   = Qb   + 2097152;
  unsigned short* VtG  = Kb   + 2097152;      // V^T [512][4096] fp16
  unsigned short* Ab   = VtG  + 2097152;      // attention output / z=1 partial
  float*          bo2  = (float*)(Ab + 2097152);  // 512 f32
  float*          mp   = bo2 + 512;           // [2][8][4096] f32 row maxes
  float*          lp   = mp + 65536;          // [2][8][4096] f32 row sums
  // high-water ~20.4 MB (ws proven >= 23 MB)
  // z=0 partial O (f32) lives in d_out, free scratch until the final gemm.

  wtrans_kernel<<<dim3(8, 8, 4), 256, 0, stream>>>(
      Wq, Wk, Wv, Wo, Wqt, Wkt, Wvt, Wot, Wof);

  // z=0..2: Q/K/V projections (A fp32; V stored transposed);
  // z=3: Wo2t = Wot @ Wof^T (M=512, x<4) + bo2 in idle tiles (x 4..11, y 0)
  gemm128_kernel<<<dim3(32, 4, 4), 256, 0, stream>>>(
      q, k, v, Wot, Wqt, Wkt, Wvt, Wof, Qb, Kb, nullptr, Wo2t,
      nullptr, VtG, Wo, bo, bo2, 0x7, 0x0);

  attn_kernel<<<dim3(32, 8, 2), 256, 0, stream>>>(
      Qb, Kb, VtG, (float*)d_out, Ab, mp, lp);

  merge_kernel<<<dim3(64, 8), 256, 0, stream>>>(
      (const float*)d_out, Ab, mp, lp, Ab);

  // single fused fc_out: d_out = Ab @ Wo2 + bo2   (fp32 out)
  gemm128_kernel<<<dim3(32, 4, 1), 256, 0, stream>>>(
      Ab, nullptr, nullptr, nullptr, Wo2t, nullptr, nullptr, nullptr,
      d_out, nullptr, nullptr, nullptr, bo2, nullptr,
      nullptr, nullptr, nullptr, 0x0, 0x1);
}

// Round 8
// 201.487 us; speedup vs baseline: 1.1231x; 1.1231x over previous
//
#include <hip/hip_runtime.h>

#define S_LEN  4096
#define DMODEL 512
#define NH     8
#define HD     64

typedef _Float16 f16x8 __attribute__((ext_vector_type(8)));
typedef _Float16 f16x4 __attribute__((ext_vector_type(4)));
typedef float    f32x4 __attribute__((ext_vector_type(4)));

static __device__ __forceinline__ unsigned short f2h(float x) {
  return __builtin_bit_cast(unsigned short, (_Float16)x);
}

// async global->LDS, 16B per lane. LDS dest is wave-uniform base + lane*16,
// so the LDS layout must be linear in lane order; swizzles are applied on
// the per-lane GLOBAL source address instead (m173 pattern).
static __device__ __forceinline__ void glds16(const void* g, void* l) {
  __builtin_amdgcn_global_load_lds(
      (const __attribute__((address_space(1))) void*)g,
      (__attribute__((address_space(3))) void*)l, 16, 0, 0);
}

// ---------------------------------------------------------------------------
// Weight transpose + fp32->fp16: Wt[n][k] = (fp16) W[k][n].  For z==3 (Wo)
// also emits the straight fp16 copy Wof[k][n].  grid (8,8,4) block 256
// ---------------------------------------------------------------------------
__global__ __launch_bounds__(256) void wtrans_kernel(
    const float* __restrict__ w0, const float* __restrict__ w1,
    const float* __restrict__ w2, const float* __restrict__ w3,
    unsigned short* __restrict__ o0, unsigned short* __restrict__ o1,
    unsigned short* __restrict__ o2, unsigned short* __restrict__ o3,
    unsigned short* __restrict__ o3s)
{
  __shared__ unsigned short T[64 * 72];   // T[n_local][k_local], pad 72
  const float* W; unsigned short* O;
  switch (blockIdx.z) {
    case 0:  W = w0; O = o0; break;
    case 1:  W = w1; O = o1; break;
    case 2:  W = w2; O = o2; break;
    default: W = w3; O = o3; break;
  }
  const int tid = threadIdx.x;
  const int k0 = blockIdx.x * 64, n0 = blockIdx.y * 64;
  const int c4 = (tid & 15) * 4;
#pragma unroll
  for (int rp = 0; rp < 4; ++rp) {
    int r = rp * 16 + (tid >> 4);
    float4 x = *(const float4*)(W + (k0 + r) * DMODEL + n0 + c4);
    T[(c4 + 0) * 72 + r] = f2h(x.x);
    T[(c4 + 1) * 72 + r] = f2h(x.y);
    T[(c4 + 2) * 72 + r] = f2h(x.z);
    T[(c4 + 3) * 72 + r] = f2h(x.w);
    if (blockIdx.z == 3) {
      f16x4 st;
      st[0] = (_Float16)x.x; st[1] = (_Float16)x.y;
      st[2] = (_Float16)x.z; st[3] = (_Float16)x.w;
      *(f16x4*)&o3s[(k0 + r) * DMODEL + n0 + c4] = st;
    }
  }
  __syncthreads();
#pragma unroll
  for (int it = 0; it < 2; ++it) {
    int i = tid + it * 256;
    int nl = i >> 3, c = i & 7;
    *(f16x8*)&O[(n0 + nl) * DMODEL + k0 + c * 8] = *(const f16x8*)&T[nl * 72 + c * 8];
  }
}

// ---------------------------------------------------------------------------
// 128x128-tile GEMM (multi-op), BK=32, 4 waves x (4x4 16x16x32 frags),
// register-prefetch staging (round-4 proven config).
// blockIdx.z selects op; z==3: x<4 -> Wo2t 128-tiles (M=512), x in 4..11 &
// y==0 -> bo2 side-job. vtg!=null && z==2: C stored transposed (V^T).
// grid (32,4,nz) block 256.
// ---------------------------------------------------------------------------
__global__ __launch_bounds__(256) void gemm128_kernel(
    const void* __restrict__ A0, const void* __restrict__ A1,
    const void* __restrict__ A2, const void* __restrict__ A3,
    const unsigned short* __restrict__ B0, const unsigned short* __restrict__ B1,
    const unsigned short* __restrict__ B2, const unsigned short* __restrict__ B3,
    void* __restrict__ C0, void* __restrict__ C1,
    void* __restrict__ C2, void* __restrict__ C3,
    const float* __restrict__ bias, unsigned short* __restrict__ vtg,
    const float* __restrict__ wo_f32, const float* __restrict__ bo_in,
    float* __restrict__ bo2_out,
    int a_fp32_mask, int c_fp32_mask)
{
  constexpr int K = DMODEL, N = DMODEL;
  __shared__ unsigned short As[128 * 32];
  __shared__ unsigned short Bs[128 * 32];
  const int z = blockIdx.z;
  if (z == 3 && blockIdx.x >= 4) {          // idle tiles: bo2 side-job
    if (blockIdx.x < 12 && blockIdx.y == 0 && wo_f32) {
      int col = (blockIdx.x - 4) * 64 + (threadIdx.x & 63);
      float s = bo_in[col];
#pragma unroll 8
      for (int j = 0; j < DMODEL; ++j) s = fmaf(bo_in[j], wo_f32[j * DMODEL + col], s);
      bo2_out[col] = s;
    }
    return;
  }
  const void* Av; const unsigned short* Bt; void* Cv;
  switch (z) {
    case 0:  Av = A0; Bt = B0; Cv = C0; break;
    case 1:  Av = A1; Bt = B1; Cv = C1; break;
    case 2:  Av = A2; Bt = B2; Cv = C2; break;
    default: Av = A3; Bt = B3; Cv = C3; break;
  }
  const int a_fp32 = (a_fp32_mask >> z) & 1;
  const int c_fp32 = (c_fp32_mask >> z) & 1;
  const int tid  = threadIdx.x;
  const int lane = tid & 63;
  const int wid  = tid >> 6;
  const int quad = lane >> 4, l16 = lane & 15;
  const int m0 = blockIdx.x * 128, n0 = blockIdx.y * 128;
  const int wm = (wid >> 1) * 64, wn = (wid & 1) * 64;
  f32x4 acc[4][4] = {};

  // staging decomposition: it in 0..1: s = it*256+tid; r = s>>2; ck = (s&3)*8
  f16x8 areg[2], breg[2];
#pragma unroll
  for (int it = 0; it < 2; ++it) {      // prefetch k0 = 0
    int s = it * 256 + tid;
    int r = s >> 2, ck = (s & 3) * 8;
    if (a_fp32) {
      const float* p = (const float*)Av + (m0 + r) * K + ck;
      float4 x = *(const float4*)p;
      float4 y = *(const float4*)(p + 4);
      f16x8 av;
      av[0] = (_Float16)x.x; av[1] = (_Float16)x.y;
      av[2] = (_Float16)x.z; av[3] = (_Float16)x.w;
      av[4] = (_Float16)y.x; av[5] = (_Float16)y.y;
      av[6] = (_Float16)y.z; av[7] = (_Float16)y.w;
      areg[it] = av;
    } else {
      areg[it] = *(const f16x8*)((const unsigned short*)Av + (m0 + r) * K + ck);
    }
    breg[it] = *(const f16x8*)(Bt + (n0 + r) * K + ck);
  }

  for (int k0 = 0; k0 < K; k0 += 32) {
    __syncthreads();
#pragma unroll
    for (int it = 0; it < 2; ++it) {
      int s = it * 256 + tid;
      int r = s >> 2, ck = (s & 3) * 8;
      *(f16x8*)&As[r * 32 + ck] = areg[it];
      *(f16x8*)&Bs[r * 32 + ck] = breg[it];
    }
    __syncthreads();

    if (k0 + 32 < K) {                  // prefetch next k-step into registers
      int kk = k0 + 32;
#pragma unroll
      for (int it = 0; it < 2; ++it) {
        int s = it * 256 + tid;
        int r = s >> 2, ck = (s & 3) * 8;
        if (a_fp32) {
          const float* p = (const float*)Av + (m0 + r) * K + kk + ck;
          float4 x = *(const float4*)p;
          float4 y = *(const float4*)(p + 4);
          f16x8 av;
          av[0] = (_Float16)x.x; av[1] = (_Float16)x.y;
          av[2] = (_Float16)x.z; av[3] = (_Float16)x.w;
          av[4] = (_Float16)y.x; av[5] = (_Float16)y.y;
          av[6] = (_Float16)y.z; av[7] = (_Float16)y.w;
          areg[it] = av;
        } else {
          areg[it] = *(const f16x8*)((const unsigned short*)Av + (m0 + r) * K + kk + ck);
        }
        breg[it] = *(const f16x8*)(Bt + (n0 + r) * K + kk + ck);
      }
    }

    f16x8 af[4], bf[4];
#pragma unroll
    for (int mt = 0; mt < 4; ++mt)
      af[mt] = *(const f16x8*)&As[(wm + mt * 16 + l16) * 32 + quad * 8];
#pragma unroll
    for (int nt = 0; nt < 4; ++nt)
      bf[nt] = *(const f16x8*)&Bs[(wn + nt * 16 + l16) * 32 + quad * 8];
#pragma unroll
    for (int mt = 0; mt < 4; ++mt)
#pragma unroll
      for (int nt = 0; nt < 4; ++nt)
        acc[mt][nt] = __builtin_amdgcn_mfma_f32_16x16x32_f16(af[mt], bf[nt], acc[mt][nt], 0, 0, 0);
  }

  const int do_vt = (vtg != nullptr) && (z == 2);
#pragma unroll
  for (int mt = 0; mt < 4; ++mt)
#pragma unroll
    for (int nt = 0; nt < 4; ++nt) {
      int col = n0 + wn + nt * 16 + l16;
      float bv = bias ? bias[col] : 0.f;
#pragma unroll
      for (int g = 0; g < 4; ++g) {
        int row = m0 + wm + mt * 16 + quad * 4 + g;   // C/D: row = quad*4+reg
        float val = acc[mt][nt][g] + bv;
        if (do_vt)        vtg[col * S_LEN + row] = f2h(val);      // V^T[d][key]
        else if (c_fp32)  ((float*)Cv)[row * N + col] = val;
        else              ((unsigned short*)Cv)[row * N + col] = f2h(val);
      }
    }
}

// ---------------------------------------------------------------------------
// Split-K MFMA flash attention, S^T formulation, 2 q-sets per wave,
// 128 q-rows per block (4 waves = 4 q-pairs), KVBLK=64 (round-6 proven;
// KVBLK=128 regressed via VGPR 148 -> occupancy 10.7%).
// ROUND CHANGES:
//  (1) Staging via global_load_lds (4 glds16/thread/iter) into LINEAR
//      double-buffered LDS; conflict-freedom via pre-swizzled GLOBAL source
//      (granule c^(row&7)); read side applies the same XOR. Removes ~80
//      staging VALU/iter and the kreg/vreg registers.
//  (2) 2-deep pipeline with counted vmcnt (m201/T3-T4 pattern): raw
//      s_barrier + "s_waitcnt vmcnt(4)" keeps next-tile loads in flight
//      across barriers. Q loads force-retired pre-loop (asm use) so the
//      vmcnt count stays exact.
//  (3) XCD-aware flat grid (512): id%8 == head, so all 64 blocks of a head
//      share one XCD's L2 (K/V working set 1 MB << 4 MB L2) -- T1.
// LDS 32.8 KB. Partials: z=0 -> f32 in d_out, z=1 -> fp16 in Ab; (m,l) to
// ws; merge_kernel combines.
// ---------------------------------------------------------------------------
__global__ __launch_bounds__(256) void attn_kernel(
    const unsigned short* __restrict__ Qb, const unsigned short* __restrict__ Kb,
    const unsigned short* __restrict__ VtG,
    float* __restrict__ P0, unsigned short* __restrict__ P1,
    float* __restrict__ mp, float* __restrict__ lp)
{
  __shared__ unsigned short Ks[2][64 * 64];   // [buf][key n][granule], linear
  __shared__ unsigned short Vt[2][64 * 64];   // [buf][d][granule], linear

  const int tid  = threadIdx.x;
  const int lane = tid & 63;
  const int wid  = tid >> 6;        // 0..3 = q-pair
  const int quad = lane >> 4, l16 = lane & 15;
  // XCD remap: id = qb*16 + (h + 8z)  =>  id%8 == h (head-per-XCD L2 locality)
  const int id = blockIdx.x;
  const int qb = id >> 4;
  const int hz = id & 15;
  const int h  = hz & 7, z = hz >> 3;
  const int hc = h * HD;
  const int qbase = qb * 128 + wid * 32;
  const int kz = z * 2048;

  // Persistent Q fragments (B operand), 2 sets: Q[q=l16][d=quad*8+j (+32)]
  f16x8 bq[2][2];
#pragma unroll
  for (int s = 0; s < 2; ++s) {
    int qrow = qbase + s * 16 + l16;
    bq[s][0] = *(const f16x8*)(Qb + qrow * DMODEL + hc + quad * 8);
    bq[s][1] = *(const f16x8*)(Qb + qrow * DMODEL + hc + 32 + quad * 8);
  }
  // Retire Q loads NOW so the loop's vmcnt counting sees only glds16 ops.
  asm volatile("" : "+v"(bq[0][0]), "+v"(bq[0][1]), "+v"(bq[1][0]), "+v"(bq[1][1]));

  // o[s][nt] holds O[q = quad*4+g][d = nt*16 + l16] for set s
  f32x4 o[2][4] = {};
  float m_run[2] = {-1e30f, -1e30f}, l_run[2] = {0.f, 0.f};

  // staging: chunk s = it*256+tid; row n = s>>3; granule c = s&7.
  // LDS dest = linear s*16B (matches glds16 base+lane*16). Global source
  // granule is pre-swizzled: c' = c ^ (n&7).
  const unsigned short *kp0, *kp1, *vp0, *vp1;
  {
    int s0 = tid, s1 = 256 + tid;
    int n0 = s0 >> 3, c0 = (s0 & 7) ^ (n0 & 7);
    int n1 = s1 >> 3, c1 = (s1 & 7) ^ (n1 & 7);
    kp0 = Kb + (kz + n0) * DMODEL + hc + c0 * 8;
    kp1 = Kb + (kz + n1) * DMODEL + hc + c1 * 8;
    vp0 = VtG + (hc + n0) * S_LEN + kz + c0 * 8;
    vp1 = VtG + (hc + n1) * S_LEN + kz + c1 * 8;
  }

  // prologue: tile 0 -> buf 0
  glds16(kp0, &Ks[0][tid * 8]);
  glds16(kp1, &Ks[0][(256 + tid) * 8]);
  glds16(vp0, &Vt[0][tid * 8]);
  glds16(vp1, &Vt[0][(256 + tid) * 8]);

  for (int kbi = 0; kbi < 32; ++kbi) {
    const int cur = kbi & 1;
    __builtin_amdgcn_s_barrier();          // all waves done reading buf[cur^1]
    if (kbi + 1 < 32) {                    // prefetch tile kbi+1 -> buf[cur^1]
      const int t = kbi + 1;
      glds16(kp0 + t * (64 * DMODEL), &Ks[cur ^ 1][tid * 8]);
      glds16(kp1 + t * (64 * DMODEL), &Ks[cur ^ 1][(256 + tid) * 8]);
      glds16(vp0 + t * 64,            &Vt[cur ^ 1][tid * 8]);
      glds16(vp1 + t * 64,            &Vt[cur ^ 1][(256 + tid) * 8]);
      asm volatile("s_waitcnt vmcnt(4)" ::: "memory");   // tile kbi landed
    } else {
      asm volatile("s_waitcnt vmcnt(0)" ::: "memory");
    }
    __builtin_amdgcn_s_barrier();          // everyone's tile-kbi data visible
    asm volatile("" ::: "memory");

    const unsigned short* KsC = Ks[cur];
    const unsigned short* VtC = Vt[cur];

    // ---- S^T = K Q^T : one Ks read feeds both q-sets
    f32x4 sT[2][4];
#pragma unroll
    for (int kt = 0; kt < 4; ++kt) {
      int r = kt * 16 + l16;
      int sw = l16 & 7;
      f16x8 ak0 = *(const f16x8*)&KsC[r * 64 + ((quad    ) ^ sw) * 8];
      f16x8 ak1 = *(const f16x8*)&KsC[r * 64 + ((quad + 4) ^ sw) * 8];
#pragma unroll
      for (int s = 0; s < 2; ++s) {
        f32x4 a = {};
        a = __builtin_amdgcn_mfma_f32_16x16x32_f16(ak0, bq[s][0], a, 0, 0, 0);
        a = __builtin_amdgcn_mfma_f32_16x16x32_f16(ak1, bq[s][1], a, 0, 0, 0);
        sT[s][kt] = a;
      }
    }

    // ---- online softmax per set (scale 1/8 folded into exp), defer-max
    f16x4 pa[2][4];
#pragma unroll
    for (int s = 0; s < 2; ++s) {
      float vmax = -1e30f;
#pragma unroll
      for (int kt = 0; kt < 4; ++kt)
#pragma unroll
        for (int g = 0; g < 4; ++g) vmax = fmaxf(vmax, sT[s][kt][g]);
      vmax = fmaxf(vmax, __shfl_xor(vmax, 16));
      vmax = fmaxf(vmax, __shfl_xor(vmax, 32));

      if (__all(vmax <= m_run[s] + 8.0f)) {
        // deferred: keep old max, no rescale; p bounded by e^1
        const float mn = m_run[s];
        float rs = 0.f;
#pragma unroll
        for (int kt = 0; kt < 4; ++kt)
#pragma unroll
          for (int g = 0; g < 4; ++g) {
            float p = __expf((sT[s][kt][g] - mn) * 0.125f);
            rs += p;
            pa[s][kt][g] = (_Float16)p;
          }
        rs += __shfl_xor(rs, 16);
        rs += __shfl_xor(rs, 32);
        l_run[s] += rs;
      } else {
        const float mn = fmaxf(m_run[s], vmax);
        const float alpha = __expf((m_run[s] - mn) * 0.125f);
        m_run[s] = mn;

        float rs = 0.f;
#pragma unroll
        for (int kt = 0; kt < 4; ++kt)
#pragma unroll
          for (int g = 0; g < 4; ++g) {
            float p = __expf((sT[s][kt][g] - mn) * 0.125f);
            rs += p;
            pa[s][kt][g] = (_Float16)p;
          }
        rs += __shfl_xor(rs, 16);
        rs += __shfl_xor(rs, 32);
        l_run[s] = l_run[s] * alpha + rs;

        float ag[4];
#pragma unroll
        for (int g = 0; g < 4; ++g) ag[g] = __shfl(alpha, quad * 4 + g);
#pragma unroll
        for (int nt = 0; nt < 4; ++nt)
#pragma unroll
          for (int g = 0; g < 4; ++g) o[s][nt][g] *= ag[g];
      }
    }

    // ---- O += P @ V : swizzled Vt b64 reads (2-way, free) feed both q-sets
#pragma unroll
    for (int nt = 0; nt < 4; ++nt) {
      int d = nt * 16 + l16;
      int sw = l16 & 7;
#pragma unroll
      for (int kt = 0; kt < 4; ++kt) {
        int u = kt * 4 + quad;                 // 8B slot within 64-key row
        f16x4 bv = *(const f16x4*)&VtC[d * 64 + (((u >> 1) ^ sw) * 8) + (u & 1) * 4];
#pragma unroll
        for (int s = 0; s < 2; ++s)
          o[s][nt] = __builtin_amdgcn_mfma_f32_16x16x16f16(pa[s][kt], bv, o[s][nt], 0, 0, 0);
      }
    }
  }

  // ---- no intra-block merge: each wave owns its 32 q-rows. Store partial.
#pragma unroll
  for (int s = 0; s < 2; ++s) {
    const float lt = l_run[s];
    const float rl = 1.f / lt;
    if (quad == 0) {                   // per-row (m,l) for cross-block merge
      int q = qbase + s * 16 + l16;
      mp[(z * NH + h) * S_LEN + q] = m_run[s];
      lp[(z * NH + h) * S_LEN + q] = lt;
    }
    float rlg[4];
#pragma unroll
    for (int g = 0; g < 4; ++g) rlg[g] = __shfl(rl, quad * 4 + g);
#pragma unroll
    for (int g = 0; g < 4; ++g) {
      int row = qbase + s * 16 + quad * 4 + g;
#pragma unroll
      for (int nt = 0; nt < 4; ++nt) {
        float val = o[s][nt][g] * rlg[g];   // normalized partial
        if (z == 0) P0[row * DMODEL + hc + nt * 16 + l16] = val;
        else        P1[row * DMODEL + hc + nt * 16 + l16] = f2h(val);
      }
    }
  }
}

// ---------------------------------------------------------------------------
// Cross-block merge of the two key-split partials: Ab = w0*P0 + w1*P1.
// grid (64, 8) block 256: thread = (row r = tid>>2, 16 d at (tid&3)*16).
// ---------------------------------------------------------------------------
__global__ __launch_bounds__(256) void merge_kernel(
    const float* __restrict__ P0, const unsigned short* __restrict__ P1,
    const float* __restrict__ mp, const float* __restrict__ lp,
    unsigned short* __restrict__ Ob)
{
  const int tid = threadIdx.x;
  const int qb = blockIdx.x, h = blockIdx.y;
  const int q = qb * 64 + (tid >> 2), hc = h * HD;
  const int dq = (tid & 3) * 16;
  const float m0 = mp[h * S_LEN + q],        l0 = lp[h * S_LEN + q];
  const float m1 = mp[(NH + h) * S_LEN + q], l1 = lp[(NH + h) * S_LEN + q];
  const float M  = fmaxf(m0, m1);
  float w0 = l0 * __expf((m0 - M) * 0.125f);
  float w1 = l1 * __expf((m1 - M) * 0.125f);
  const float rw = 1.f / (w0 + w1);
  w0 *= rw; w1 *= rw;
  const int base = q * DMODEL + hc + dq;
  f16x8 p1a = *(const f16x8*)&P1[base];
  f16x8 p1b = *(const f16x8*)&P1[base + 8];
  float4 x0 = *(const float4*)&P0[base];
  float4 x1 = *(const float4*)&P0[base + 4];
  float4 x2 = *(const float4*)&P0[base + 8];
  float4 x3 = *(const float4*)&P0[base + 12];
  f16x8 oa, ob;
  oa[0] = (_Float16)(w0 * x0.x + w1 * (float)p1a[0]);
  oa[1] = (_Float16)(w0 * x0.y + w1 * (float)p1a[1]);
  oa[2] = (_Float16)(w0 * x0.z + w1 * (float)p1a[2]);
  oa[3] = (_Float16)(w0 * x0.w + w1 * (float)p1a[3]);
  oa[4] = (_Float16)(w0 * x1.x + w1 * (float)p1a[4]);
  oa[5] = (_Float16)(w0 * x1.y + w1 * (float)p1a[5]);
  oa[6] = (_Float16)(w0 * x1.z + w1 * (float)p1a[6]);
  oa[7] = (_Float16)(w0 * x1.w + w1 * (float)p1a[7]);
  ob[0] = (_Float16)(w0 * x2.x + w1 * (float)p1b[0]);
  ob[1] = (_Float16)(w0 * x2.y + w1 * (float)p1b[1]);
  ob[2] = (_Float16)(w0 * x2.z + w1 * (float)p1b[2]);
  ob[3] = (_Float16)(w0 * x2.w + w1 * (float)p1b[3]);
  ob[4] = (_Float16)(w0 * x3.x + w1 * (float)p1b[4]);
  ob[5] = (_Float16)(w0 * x3.y + w1 * (float)p1b[5]);
  ob[6] = (_Float16)(w0 * x3.z + w1 * (float)p1b[6]);
  ob[7] = (_Float16)(w0 * x3.w + w1 * (float)p1b[7]);
  *(f16x8*)&Ob[base]     = oa;
  *(f16x8*)&Ob[base + 8] = ob;
}

// ---------------------------------------------------------------------------
extern "C" void kernel_launch(void* const* d_in, const int* in_sizes, int n_in,
                              void* d_out, int out_size, void* d_ws, size_t ws_size,
                              hipStream_t stream) {
  const float* q  = (const float*)d_in[0];
  const float* k  = (const float*)d_in[1];
  const float* v  = (const float*)d_in[2];
  const float* Wq = (const float*)d_in[3];
  const float* Wk = (const float*)d_in[4];
  const float* Wv = (const float*)d_in[5];
  const float* Wo = (const float*)d_in[6];
  const float* bo = (const float*)d_in[7];

  unsigned short* ws   = (unsigned short*)d_ws;
  unsigned short* Wqt  = ws;                  // 512*512 fp16 each
  unsigned short* Wkt  = Wqt  + 262144;
  unsigned short* Wvt  = Wkt  + 262144;
  unsigned short* Wot  = Wvt  + 262144;
  unsigned short* Wof  = Wot  + 262144;       // straight fp16 Wo
  unsigned short* Wo2t = Wof  + 262144;       // (Wo^2)^T fp16
  unsigned short* Qb   = Wo2t + 262144;       // 4096*512 fp16 each
  unsigned short* Kb   = Qb   + 2097152;
  unsigned short* VtG  = Kb   + 2097152;      // V^T [512][4096] fp16
  unsigned short* Ab   = VtG  + 2097152;      // attention output / z=1 partial
  float*          bo2  = (float*)(Ab + 2097152);  // 512 f32
  float*          mp   = bo2 + 512;           // [2][8][4096] f32 row maxes
  float*          lp   = mp + 65536;          // [2][8][4096] f32 row sums
  // high-water ~20.4 MB (ws proven >= 23 MB)
  // z=0 partial O (f32) lives in d_out, free scratch until the final gemm.

  wtrans_kernel<<<dim3(8, 8, 4), 256, 0, stream>>>(
      Wq, Wk, Wv, Wo, Wqt, Wkt, Wvt, Wot, Wof);

  // z=0..2: Q/K/V projections (A fp32; V stored transposed);
  // z=3: Wo2t = Wot @ Wof^T (M=512, x<4) + bo2 in idle tiles (x 4..11, y 0)
  gemm128_kernel<<<dim3(32, 4, 4), 256, 0, stream>>>(
      q, k, v, Wot, Wqt, Wkt, Wvt, Wof, Qb, Kb, nullptr, Wo2t,
      nullptr, VtG, Wo, bo, bo2, 0x7, 0x0);

  // flat 512-block grid (XCD remap inside kernel)
  attn_kernel<<<dim3(512), 256, 0, stream>>>(
      Qb, Kb, VtG, (float*)d_out, Ab, mp, lp);

  merge_kernel<<<dim3(64, 8), 256, 0, stream>>>(
      (const float*)d_out, Ab, mp, lp, Ab);

  // single fused fc_out: d_out = Ab @ Wo2 + bo2   (fp32 out)
  gemm128_kernel<<<dim3(32, 4, 1), 256, 0, stream>>>(
      Ab, nullptr, nullptr, nullptr, Wo2t, nullptr, nullptr, nullptr,
      d_out, nullptr, nullptr, nullptr, bo2, nullptr,
      nullptr, nullptr, nullptr, 0x0, 0x1);
}